// Round 7
// baseline (486.769 us; speedup 1.0000x reference)
//
#include <hip/hip_runtime.h>

#define N_NODES 100000
#define N_EDGES 600000
#define K_DIM 128
#define M2 64

using frag_ab = __attribute__((ext_vector_type(8))) short;   // 8 bf16 = 4 VGPRs
using frag_cd = __attribute__((ext_vector_type(4))) float;   // 4 fp32 acc

// fp32 -> bf16 round-to-nearest-even
__device__ __forceinline__ unsigned short f2b(float f) {
  unsigned u = __builtin_bit_cast(unsigned, f);
  u = (u + 0x7fffu + ((u >> 16) & 1u)) >> 16;
  return (unsigned short)u;
}

// ---------------- fused conversion: x -> bf16, plus 4 weight transposes ----------------
// blocks [0, XB) convert x (float4 granularity); blocks [XB, XB+WB) do weights.
#define XB_BLOCKS ((N_NODES * K_DIM / 4 + 255) / 256)            // 12500
#define W_ELEMS ((128 + 128 + 64 + 64) * 128)                    // 49152
#define WB_BLOCKS ((W_ELEMS + 255) / 256)                        // 192
__global__ __launch_bounds__(256) void conv_all(const float* __restrict__ x,
                                                unsigned short* __restrict__ xb,
                                                const float* __restrict__ Ws1,
                                                const float* __restrict__ Wn1,
                                                const float* __restrict__ Ws2,
                                                const float* __restrict__ Wn2,
                                                unsigned short* __restrict__ Ws1T,
                                                unsigned short* __restrict__ Wn1T,
                                                unsigned short* __restrict__ Ws2T,
                                                unsigned short* __restrict__ Wn2T) {
  if (blockIdx.x < XB_BLOCKS) {
    long i = (long)blockIdx.x * 256 + threadIdx.x;
    if (i >= (long)N_NODES * K_DIM / 4) return;
    float4 v = *(const float4*)(x + i * 4);
    ushort4 o;
    o.x = f2b(v.x); o.y = f2b(v.y); o.z = f2b(v.z); o.w = f2b(v.w);
    *(ushort4*)(xb + i * 4) = o;
  } else {
    int i = (blockIdx.x - XB_BLOCKS) * 256 + threadIdx.x;  // global weight elem
    if (i >= W_ELEMS) return;
    const float* W;
    unsigned short* WT;
    int M, li;
    if (i < 128 * 128)               { W = Ws1; WT = Ws1T; M = 128; li = i; }
    else if (i < 2 * 128 * 128)      { W = Wn1; WT = Wn1T; M = 128; li = i - 128 * 128; }
    else if (i < 2 * 128 * 128 + 64 * 128) { W = Ws2; WT = Ws2T; M = 64; li = i - 2 * 128 * 128; }
    else                             { W = Wn2; WT = Wn2T; M = 64; li = i - 2 * 128 * 128 - 64 * 128; }
    int n = li >> 7, k = li & 127;   // li = n*128 + k
    WT[li] = f2b(W[k * M + n]);
  }
}

// ---------------- degree count ----------------
__global__ __launch_bounds__(256) void deg_count(const int* __restrict__ dst,
                                                 int* __restrict__ deg, int nE) {
  int i = blockIdx.x * blockDim.x + threadIdx.x;
  if (i < nE) atomicAdd(&deg[dst[i]], 1);
}

// ---------------- single-workgroup exclusive scan: deg -> row_ptr, cursor ----------------
// 1024 threads, each owns a contiguous chunk of ceil(n/1024) elements.
__global__ __launch_bounds__(1024) void scan_single(const int* __restrict__ deg,
                                                    int* __restrict__ row_ptr,
                                                    int* __restrict__ cursor, int n, int nE) {
  __shared__ int sums[1024];
  const int tid = threadIdx.x;
  const int chunk = (n + 1023) / 1024;
  const int beg = tid * chunk;
  const int end = min(beg + chunk, n);

  int s = 0;
  for (int i = beg; i < end; ++i) s += deg[i];
  sums[tid] = s;
  __syncthreads();
  // Hillis-Steele inclusive scan over 1024 thread sums
  for (int off = 1; off < 1024; off <<= 1) {
    int t = (tid >= off) ? sums[tid - off] : 0;
    __syncthreads();
    sums[tid] += t;
    __syncthreads();
  }
  int run = sums[tid] - s;  // exclusive prefix of this thread's chunk
  for (int i = beg; i < end; ++i) {
    row_ptr[i] = run;
    cursor[i] = run;
    run += deg[i];
  }
  if (tid == 0) row_ptr[n] = nE;
}

// ---------------- CSR fill ----------------
__global__ __launch_bounds__(256) void csr_fill(const int* __restrict__ src,
                                                const int* __restrict__ dst,
                                                int* __restrict__ cursor,
                                                int* __restrict__ csr_src, int nE) {
  int e = blockIdx.x * blockDim.x + threadIdx.x;
  if (e < nE) {
    int pos = atomicAdd(&cursor[dst[e]], 1);
    csr_src[pos] = src[e];
  }
}

// ---------------- gather-mean, 128 bf16 cols: 16 threads/node, 4-way pipelined ----------------
__global__ __launch_bounds__(256) void aggregate128(const unsigned short* __restrict__ xb,
                                                    const int* __restrict__ row_ptr,
                                                    const int* __restrict__ csr_src,
                                                    unsigned short* __restrict__ agg, int n) {
  int t = blockIdx.x * blockDim.x + threadIdx.x;
  int node = t >> 4;
  int c = (t & 15) << 3;  // 8 bf16 per thread
  if (node >= n) return;
  int beg = row_ptr[node], end = row_ptr[node + 1];
  float acc[8];
#pragma unroll
  for (int j = 0; j < 8; ++j) acc[j] = 0.f;

  int e = beg;
  for (; e + 4 <= end; e += 4) {
    int s0 = csr_src[e], s1 = csr_src[e + 1], s2 = csr_src[e + 2], s3 = csr_src[e + 3];
    uint4 v0 = *(const uint4*)(xb + (size_t)s0 * K_DIM + c);
    uint4 v1 = *(const uint4*)(xb + (size_t)s1 * K_DIM + c);
    uint4 v2 = *(const uint4*)(xb + (size_t)s2 * K_DIM + c);
    uint4 v3 = *(const uint4*)(xb + (size_t)s3 * K_DIM + c);
    unsigned u[4][4] = {{v0.x, v0.y, v0.z, v0.w}, {v1.x, v1.y, v1.z, v1.w},
                        {v2.x, v2.y, v2.z, v2.w}, {v3.x, v3.y, v3.z, v3.w}};
#pragma unroll
    for (int p = 0; p < 4; ++p)
#pragma unroll
      for (int j = 0; j < 4; ++j) {
        acc[2 * j]     += __builtin_bit_cast(float, u[p][j] << 16);
        acc[2 * j + 1] += __builtin_bit_cast(float, u[p][j] & 0xffff0000u);
      }
  }
  for (; e < end; ++e) {
    int s = csr_src[e];
    uint4 v = *(const uint4*)(xb + (size_t)s * K_DIM + c);
    unsigned u[4] = {v.x, v.y, v.z, v.w};
#pragma unroll
    for (int j = 0; j < 4; ++j) {
      acc[2 * j]     += __builtin_bit_cast(float, u[j] << 16);
      acc[2 * j + 1] += __builtin_bit_cast(float, u[j] & 0xffff0000u);
    }
  }
  float inv = 1.0f / (float)max(end - beg, 1);
  uint4 o;
  unsigned* op = (unsigned*)&o;
#pragma unroll
  for (int j = 0; j < 4; ++j) {
    unsigned lo = f2b(acc[2 * j] * inv);
    unsigned hi = f2b(acc[2 * j + 1] * inv);
    op[j] = lo | (hi << 16);
  }
  *(uint4*)(agg + (size_t)node * K_DIM + c) = o;
}

// ---------------- gather-mean-add, 64 bf16 cols -> out fp32: 8 threads/node, 4-way pipelined ----------------
__global__ __launch_bounds__(256) void aggregate64_add(const unsigned short* __restrict__ g,
                                                       const int* __restrict__ row_ptr,
                                                       const int* __restrict__ csr_src,
                                                       float* __restrict__ out, int n) {
  int t = blockIdx.x * blockDim.x + threadIdx.x;
  int node = t >> 3;
  int c = (t & 7) << 3;  // 8 bf16 per thread
  if (node >= n) return;
  int beg = row_ptr[node], end = row_ptr[node + 1];
  float acc[8];
#pragma unroll
  for (int j = 0; j < 8; ++j) acc[j] = 0.f;

  int e = beg;
  for (; e + 4 <= end; e += 4) {
    int s0 = csr_src[e], s1 = csr_src[e + 1], s2 = csr_src[e + 2], s3 = csr_src[e + 3];
    uint4 v0 = *(const uint4*)(g + (size_t)s0 * M2 + c);
    uint4 v1 = *(const uint4*)(g + (size_t)s1 * M2 + c);
    uint4 v2 = *(const uint4*)(g + (size_t)s2 * M2 + c);
    uint4 v3 = *(const uint4*)(g + (size_t)s3 * M2 + c);
    unsigned u[4][4] = {{v0.x, v0.y, v0.z, v0.w}, {v1.x, v1.y, v1.z, v1.w},
                        {v2.x, v2.y, v2.z, v2.w}, {v3.x, v3.y, v3.z, v3.w}};
#pragma unroll
    for (int p = 0; p < 4; ++p)
#pragma unroll
      for (int j = 0; j < 4; ++j) {
        acc[2 * j]     += __builtin_bit_cast(float, u[p][j] << 16);
        acc[2 * j + 1] += __builtin_bit_cast(float, u[p][j] & 0xffff0000u);
      }
  }
  for (; e < end; ++e) {
    int s = csr_src[e];
    uint4 v = *(const uint4*)(g + (size_t)s * M2 + c);
    unsigned u[4] = {v.x, v.y, v.z, v.w};
#pragma unroll
    for (int j = 0; j < 4; ++j) {
      acc[2 * j]     += __builtin_bit_cast(float, u[j] << 16);
      acc[2 * j + 1] += __builtin_bit_cast(float, u[j] & 0xffff0000u);
    }
  }
  float inv = 1.0f / (float)max(end - beg, 1);
  float* op = out + (size_t)node * M2 + c;
  float4 o0 = *(float4*)(op);
  float4 o1 = *(float4*)(op + 4);
  o0.x += acc[0] * inv; o0.y += acc[1] * inv; o0.z += acc[2] * inv; o0.w += acc[3] * inv;
  o1.x += acc[4] * inv; o1.y += acc[5] * inv; o1.z += acc[6] * inv; o1.w += acc[7] * inv;
  *(float4*)(op) = o0;
  *(float4*)(op + 4) = o1;
}

// ---------------- fused both-layer GEMM, 128-node blocks (R5 structure: 53 us) ----------------
// Phase 1: h1 = relu(xb@Ws1 + aggb@Wn1 + b1) -> LDS (128 nodes x 128 feat)
// Phase 2: out = h1@Ws2 + b2 (fp32), g = h1@Wn2 (bf16)
// Operand-swapped MFMA: A = weight rows (feat=lane&15), B = node rows (node=lane&15);
// D: node = lane&15, feat = q*4+r -> vectorized stores.
#define LD1 132   // LDS row stride (264 B)
__global__ __launch_bounds__(256) void sage_fused_gemm(const unsigned short* __restrict__ xb,
                                                       const unsigned short* __restrict__ aggb,
                                                       const unsigned short* __restrict__ Ws1T,
                                                       const unsigned short* __restrict__ Wn1T,
                                                       const float* __restrict__ b1,
                                                       const unsigned short* __restrict__ Ws2T,
                                                       const unsigned short* __restrict__ Wn2T,
                                                       const float* __restrict__ b2,
                                                       float* __restrict__ out,
                                                       unsigned short* __restrict__ g, int N) {
  __shared__ unsigned short h1s[128 * LD1];

  const int tid = threadIdx.x;
  const int wave = tid >> 6;
  const int lane = tid & 63;
  const int l15 = lane & 15;
  const int q = lane >> 4;
  const int nodehalf = wave >> 1;
  const int fhalf = wave & 1;
  const int nbase_l = nodehalf * 64;
  const int nbase_g = blockIdx.x * 128 + nbase_l;
  const int fbase = fhalf * 64;

  // ---- phase 1: prefetch all x/agg fragments (32 outstanding 16-B loads) ----
  frag_ab ax[4][4], ag[4][4];
#pragma unroll
  for (int nt = 0; nt < 4; ++nt) {
    int m = nbase_g + nt * 16 + l15;
    int mc = (m < N) ? m : (N - 1);
    const unsigned short* xr = xb + (size_t)mc * K_DIM + q * 8;
    const unsigned short* gr = aggb + (size_t)mc * K_DIM + q * 8;
#pragma unroll
    for (int kb = 0; kb < 4; ++kb) {
      ax[nt][kb] = *(const frag_ab*)(xr + kb * 32);
      ag[nt][kb] = *(const frag_ab*)(gr + kb * 32);
    }
  }

  frag_cd acc[4][4];  // [nt][ft]
#pragma unroll
  for (int nt = 0; nt < 4; ++nt)
#pragma unroll
    for (int ft = 0; ft < 4; ++ft) acc[nt][ft] = (frag_cd)(0.f);

  const unsigned short* wsp = Ws1T + (size_t)(fbase + l15) * K_DIM + q * 8;
  const unsigned short* wnp = Wn1T + (size_t)(fbase + l15) * K_DIM + q * 8;
#pragma unroll
  for (int kb = 0; kb < 4; ++kb) {
#pragma unroll
    for (int ft = 0; ft < 4; ++ft) {
      frag_ab fs = *(const frag_ab*)(wsp + ft * (16 * K_DIM) + kb * 32);
      frag_ab fn = *(const frag_ab*)(wnp + ft * (16 * K_DIM) + kb * 32);
#pragma unroll
      for (int nt = 0; nt < 4; ++nt) {
        acc[nt][ft] = __builtin_amdgcn_mfma_f32_16x16x32_bf16(fs, ax[nt][kb], acc[nt][ft], 0, 0, 0);
        acc[nt][ft] = __builtin_amdgcn_mfma_f32_16x16x32_bf16(fn, ag[nt][kb], acc[nt][ft], 0, 0, 0);
      }
    }
  }

  // epilogue 1: relu(acc + b1) -> LDS, 8-B stores (4 consecutive feats per lane)
#pragma unroll
  for (int ft = 0; ft < 4; ++ft) {
    int f0 = fbase + ft * 16 + q * 4;
    float4 bv = *(const float4*)(b1 + f0);
#pragma unroll
    for (int nt = 0; nt < 4; ++nt) {
      int nl = nbase_l + nt * 16 + l15;
      ushort4 o;
      o.x = f2b(fmaxf(acc[nt][ft][0] + bv.x, 0.f));
      o.y = f2b(fmaxf(acc[nt][ft][1] + bv.y, 0.f));
      o.z = f2b(fmaxf(acc[nt][ft][2] + bv.z, 0.f));
      o.w = f2b(fmaxf(acc[nt][ft][3] + bv.w, 0.f));
      *(ushort4*)(h1s + nl * LD1 + f0) = o;
    }
  }
  __syncthreads();

  // ---- phase 2: h1 fragments from LDS ----
  frag_ab ah[4][4];
#pragma unroll
  for (int nt = 0; nt < 4; ++nt) {
    const unsigned short* hr = h1s + (nbase_l + nt * 16 + l15) * LD1 + q * 8;
#pragma unroll
    for (int kb = 0; kb < 4; ++kb) ah[nt][kb] = *(const frag_ab*)(hr + kb * 32);
  }

  const unsigned short* W2 = fhalf ? Wn2T : Ws2T;  // wave's output matrix
  const unsigned short* wp = W2 + (size_t)l15 * K_DIM + q * 8;
  frag_cd acc2[4][4];
#pragma unroll
  for (int nt = 0; nt < 4; ++nt)
#pragma unroll
    for (int ft = 0; ft < 4; ++ft) acc2[nt][ft] = (frag_cd)(0.f);

#pragma unroll
  for (int kb = 0; kb < 4; ++kb) {
#pragma unroll
    for (int ft = 0; ft < 4; ++ft) {
      frag_ab wf = *(const frag_ab*)(wp + ft * (16 * K_DIM) + kb * 32);
#pragma unroll
      for (int nt = 0; nt < 4; ++nt)
        acc2[nt][ft] = __builtin_amdgcn_mfma_f32_16x16x32_bf16(wf, ah[nt][kb], acc2[nt][ft], 0, 0, 0);
    }
  }

  // epilogue 2: fhalf==0 -> out fp32 (+b2), fhalf==1 -> g bf16
  if (fhalf == 0) {
#pragma unroll
    for (int ft = 0; ft < 4; ++ft) {
      int f0 = ft * 16 + q * 4;
      float4 bv = *(const float4*)(b2 + f0);
#pragma unroll
      for (int nt = 0; nt < 4; ++nt) {
        int node = nbase_g + nt * 16 + l15;
        if (node < N) {
          float4 o;
          o.x = acc2[nt][ft][0] + bv.x;
          o.y = acc2[nt][ft][1] + bv.y;
          o.z = acc2[nt][ft][2] + bv.z;
          o.w = acc2[nt][ft][3] + bv.w;
          *(float4*)(out + (size_t)node * M2 + f0) = o;
        }
      }
    }
  } else {
#pragma unroll
    for (int ft = 0; ft < 4; ++ft) {
      int f0 = ft * 16 + q * 4;
#pragma unroll
      for (int nt = 0; nt < 4; ++nt) {
        int node = nbase_g + nt * 16 + l15;
        if (node < N) {
          ushort4 o;
          o.x = f2b(acc2[nt][ft][0]);
          o.y = f2b(acc2[nt][ft][1]);
          o.z = f2b(acc2[nt][ft][2]);
          o.w = f2b(acc2[nt][ft][3]);
          *(ushort4*)(g + (size_t)node * M2 + f0) = o;
        }
      }
    }
  }
}

extern "C" void kernel_launch(void* const* d_in, const int* in_sizes, int n_in,
                              void* d_out, int out_size, void* d_ws, size_t ws_size,
                              hipStream_t stream) {
  const float* x   = (const float*)d_in[0];
  const int*   src = (const int*)d_in[1];
  const int*   dst = (const int*)d_in[2];
  const float* Ws1 = (const float*)d_in[3];
  const float* Wn1 = (const float*)d_in[4];
  const float* b1  = (const float*)d_in[5];
  const float* Ws2 = (const float*)d_in[6];
  const float* Wn2 = (const float*)d_in[7];
  const float* b2  = (const float*)d_in[8];
  float* out = (float*)d_out;

  char* ws = (char*)d_ws;
  size_t off = 0;
  auto alloc = [&](size_t bytes) {
    void* p = ws + off;
    off = (off + bytes + 4095) & ~(size_t)4095;
    return p;
  };
  int* deg       = (int*)alloc((size_t)N_NODES * 4);
  int* row_ptr   = (int*)alloc((size_t)(N_NODES + 1) * 4);
  int* cursor    = (int*)alloc((size_t)N_NODES * 4);
  int* csr_src   = (int*)alloc((size_t)N_EDGES * 4);
  unsigned short* xb   = (unsigned short*)alloc((size_t)N_NODES * K_DIM * 2);
  unsigned short* aggb = (unsigned short*)alloc((size_t)N_NODES * K_DIM * 2);
  unsigned short* g    = (unsigned short*)alloc((size_t)N_NODES * M2 * 2);
  unsigned short* Ws1T = (unsigned short*)alloc((size_t)128 * 128 * 2);
  unsigned short* Wn1T = (unsigned short*)alloc((size_t)128 * 128 * 2);
  unsigned short* Ws2T = (unsigned short*)alloc((size_t)64 * 128 * 2);
  unsigned short* Wn2T = (unsigned short*)alloc((size_t)64 * 128 * 2);

  hipMemsetAsync(deg, 0, (size_t)N_NODES * 4, stream);

  // fused conversions (x -> bf16, 4 weight transposes)
  conv_all<<<XB_BLOCKS + WB_BLOCKS, 256, 0, stream>>>(
      x, xb, Ws1, Wn1, Ws2, Wn2, Ws1T, Wn1T, Ws2T, Wn2T);

  // CSR build: deg -> single-WG scan -> fill
  deg_count<<<(N_EDGES + 255) / 256, 256, 0, stream>>>(dst, deg, N_EDGES);
  scan_single<<<1, 1024, 0, stream>>>(deg, row_ptr, cursor, N_NODES, N_EDGES);
  csr_fill<<<(N_EDGES + 255) / 256, 256, 0, stream>>>(src, dst, cursor, csr_src, N_EDGES);

  // layer-1 aggregation
  {
    long t = (long)N_NODES * 16;
    aggregate128<<<(int)((t + 255) / 256), 256, 0, stream>>>(xb, row_ptr, csr_src, aggb, N_NODES);
  }

  // fused layer-1 + layer-2 GEMMs (h1 stays in LDS)
  sage_fused_gemm<<<(N_NODES + 127) / 128, 256, 0, stream>>>(
      xb, aggb, Ws1T, Wn1T, b1, Ws2T, Wn2T, b2, out, g, N_NODES);

  // layer-2 aggregation (adds mean(g) into out)
  {
    long t = (long)N_NODES * 8;
    aggregate64_add<<<(int)((t + 255) / 256), 256, 0, stream>>>(g, row_ptr, csr_src, out, N_NODES);
  }
}

// Round 8
// 343.084 us; speedup vs baseline: 1.4188x; 1.4188x over previous
//
#include <hip/hip_runtime.h>

#define N_NODES 100000
#define N_EDGES 600000
#define K_DIM 128
#define M2 64
#define SCAN_BLOCKS ((N_NODES + 255) / 256)   // 391

using frag_ab = __attribute__((ext_vector_type(8))) short;   // 8 bf16 = 4 VGPRs
using frag_cd = __attribute__((ext_vector_type(4))) float;   // 4 fp32 acc

// fp32 -> bf16 round-to-nearest-even
__device__ __forceinline__ unsigned short f2b(float f) {
  unsigned u = __builtin_bit_cast(unsigned, f);
  u = (u + 0x7fffu + ((u >> 16) & 1u)) >> 16;
  return (unsigned short)u;
}

// ---------------- fused conversion: x -> bf16, plus 4 weight transposes ----------------
#define XB_BLOCKS ((N_NODES * K_DIM / 4 + 255) / 256)            // 12500
#define W_ELEMS ((128 + 128 + 64 + 64) * 128)                    // 49152
#define WB_BLOCKS ((W_ELEMS + 255) / 256)                        // 192
__global__ __launch_bounds__(256) void conv_all(const float* __restrict__ x,
                                                unsigned short* __restrict__ xb,
                                                const float* __restrict__ Ws1,
                                                const float* __restrict__ Wn1,
                                                const float* __restrict__ Ws2,
                                                const float* __restrict__ Wn2,
                                                unsigned short* __restrict__ Ws1T,
                                                unsigned short* __restrict__ Wn1T,
                                                unsigned short* __restrict__ Ws2T,
                                                unsigned short* __restrict__ Wn2T) {
  if (blockIdx.x < XB_BLOCKS) {
    long i = (long)blockIdx.x * 256 + threadIdx.x;
    if (i >= (long)N_NODES * K_DIM / 4) return;
    float4 v = *(const float4*)(x + i * 4);
    ushort4 o;
    o.x = f2b(v.x); o.y = f2b(v.y); o.z = f2b(v.z); o.w = f2b(v.w);
    *(ushort4*)(xb + i * 4) = o;
  } else {
    int i = (blockIdx.x - XB_BLOCKS) * 256 + threadIdx.x;  // global weight elem
    if (i >= W_ELEMS) return;
    const float* W;
    unsigned short* WT;
    int M, li;
    if (i < 128 * 128)               { W = Ws1; WT = Ws1T; M = 128; li = i; }
    else if (i < 2 * 128 * 128)      { W = Wn1; WT = Wn1T; M = 128; li = i - 128 * 128; }
    else if (i < 2 * 128 * 128 + 64 * 128) { W = Ws2; WT = Ws2T; M = 64; li = i - 2 * 128 * 128; }
    else                             { W = Wn2; WT = Wn2T; M = 64; li = i - 2 * 128 * 128 - 64 * 128; }
    int n = li >> 7, k = li & 127;   // li = n*128 + k
    WT[li] = f2b(W[k * M + n]);
  }
}

// ---------------- degree count ----------------
__global__ __launch_bounds__(256) void deg_count(const int* __restrict__ dst,
                                                 int* __restrict__ deg, int nE) {
  int i = blockIdx.x * blockDim.x + threadIdx.x;
  if (i < nE) atomicAdd(&deg[dst[i]], 1);
}

// ---------------- hierarchical exclusive scan (proven: ~10 us total) ----------------
__global__ __launch_bounds__(256) void scan1(const int* __restrict__ deg,
                                             int* __restrict__ partial,
                                             int* __restrict__ blockSums, int n) {
  __shared__ int sdata[256];
  int tid = threadIdx.x;
  int i = blockIdx.x * 256 + tid;
  int v = (i < n) ? deg[i] : 0;
  sdata[tid] = v;
  __syncthreads();
#pragma unroll
  for (int off = 1; off < 256; off <<= 1) {
    int t = (tid >= off) ? sdata[tid - off] : 0;
    __syncthreads();
    sdata[tid] += t;
    __syncthreads();
  }
  if (i < n) partial[i] = sdata[tid] - v;
  if (tid == 255) blockSums[blockIdx.x] = sdata[255];
}

__global__ __launch_bounds__(512) void scan2(int* __restrict__ blockSums, int nb) {
  __shared__ int sdata[512];
  int tid = threadIdx.x;
  int v = (tid < nb) ? blockSums[tid] : 0;
  sdata[tid] = v;
  __syncthreads();
#pragma unroll
  for (int off = 1; off < 512; off <<= 1) {
    int t = (tid >= off) ? sdata[tid - off] : 0;
    __syncthreads();
    sdata[tid] += t;
    __syncthreads();
  }
  if (tid < nb) blockSums[tid] = sdata[tid] - v;
}

__global__ __launch_bounds__(256) void scan3(int* __restrict__ row_ptr,
                                             const int* __restrict__ blockSums,
                                             int* __restrict__ cursor, int n, int nE) {
  int i = blockIdx.x * 256 + threadIdx.x;
  if (i < n) {
    int val = row_ptr[i] + blockSums[i >> 8];
    row_ptr[i] = val;
    cursor[i] = val;
  }
  if (i == 0) row_ptr[n] = nE;
}

// ---------------- CSR fill ----------------
__global__ __launch_bounds__(256) void csr_fill(const int* __restrict__ src,
                                                const int* __restrict__ dst,
                                                int* __restrict__ cursor,
                                                int* __restrict__ csr_src, int nE) {
  int e = blockIdx.x * blockDim.x + threadIdx.x;
  if (e < nE) {
    int pos = atomicAdd(&cursor[dst[e]], 1);
    csr_src[pos] = src[e];
  }
}

// ---------------- gather-mean-add, 64 bf16 cols -> out fp32: 8 threads/node, 4-way pipelined ----------------
__global__ __launch_bounds__(256) void aggregate64_add(const unsigned short* __restrict__ g,
                                                       const int* __restrict__ row_ptr,
                                                       const int* __restrict__ csr_src,
                                                       float* __restrict__ out, int n) {
  int t = blockIdx.x * blockDim.x + threadIdx.x;
  int node = t >> 3;
  int c = (t & 7) << 3;  // 8 bf16 per thread
  if (node >= n) return;
  int beg = row_ptr[node], end = row_ptr[node + 1];
  float acc[8];
#pragma unroll
  for (int j = 0; j < 8; ++j) acc[j] = 0.f;

  int e = beg;
  for (; e + 4 <= end; e += 4) {
    int s0 = csr_src[e], s1 = csr_src[e + 1], s2 = csr_src[e + 2], s3 = csr_src[e + 3];
    uint4 v0 = *(const uint4*)(g + (size_t)s0 * M2 + c);
    uint4 v1 = *(const uint4*)(g + (size_t)s1 * M2 + c);
    uint4 v2 = *(const uint4*)(g + (size_t)s2 * M2 + c);
    uint4 v3 = *(const uint4*)(g + (size_t)s3 * M2 + c);
    unsigned u[4][4] = {{v0.x, v0.y, v0.z, v0.w}, {v1.x, v1.y, v1.z, v1.w},
                        {v2.x, v2.y, v2.z, v2.w}, {v3.x, v3.y, v3.z, v3.w}};
#pragma unroll
    for (int p = 0; p < 4; ++p)
#pragma unroll
      for (int j = 0; j < 4; ++j) {
        acc[2 * j]     += __builtin_bit_cast(float, u[p][j] << 16);
        acc[2 * j + 1] += __builtin_bit_cast(float, u[p][j] & 0xffff0000u);
      }
  }
  for (; e < end; ++e) {
    int s = csr_src[e];
    uint4 v = *(const uint4*)(g + (size_t)s * M2 + c);
    unsigned u[4] = {v.x, v.y, v.z, v.w};
#pragma unroll
    for (int j = 0; j < 4; ++j) {
      acc[2 * j]     += __builtin_bit_cast(float, u[j] << 16);
      acc[2 * j + 1] += __builtin_bit_cast(float, u[j] & 0xffff0000u);
    }
  }
  float inv = 1.0f / (float)max(end - beg, 1);
  float* op = out + (size_t)node * M2 + c;
  float4 o0 = *(float4*)(op);
  float4 o1 = *(float4*)(op + 4);
  o0.x += acc[0] * inv; o0.y += acc[1] * inv; o0.z += acc[2] * inv; o0.w += acc[3] * inv;
  o1.x += acc[4] * inv; o1.y += acc[5] * inv; o1.z += acc[6] * inv; o1.w += acc[7] * inv;
  *(float4*)(op) = o0;
  *(float4*)(op + 4) = o1;
}

// ---------------- fully-fused: gather-mean (phase 0) + both GEMM layers ----------------
// Phase 0: aggs[nl] = mean_{e in CSR[node]} xb[src]  (LDS, 16 threads/node)
// Phase 1: h1 = relu(xb@Ws1 + aggs@Wn1 + b1) -> LDS
// Phase 2: out = h1@Ws2 + b2 (fp32), g = h1@Wn2 (bf16)
// Operand-swapped MFMA: A = weight rows (feat=lane&15), B = node rows (node=lane&15);
// D: node = lane&15, feat = q*4+r -> vectorized stores.
#define LDA 136   // aggs stride in shorts (272 B: 16B-aligned rows, bank step 4 -> min-cycle reads)
#define LD1 132   // h1s stride in shorts (264 B)
__global__ __launch_bounds__(256) void sage_fused_gemm(const unsigned short* __restrict__ xb,
                                                       const int* __restrict__ row_ptr,
                                                       const int* __restrict__ csr_src,
                                                       const unsigned short* __restrict__ Ws1T,
                                                       const unsigned short* __restrict__ Wn1T,
                                                       const float* __restrict__ b1,
                                                       const unsigned short* __restrict__ Ws2T,
                                                       const unsigned short* __restrict__ Wn2T,
                                                       const float* __restrict__ b2,
                                                       float* __restrict__ out,
                                                       unsigned short* __restrict__ g, int N) {
  __shared__ unsigned short aggs[128 * LDA];  // 34.8 KB
  __shared__ unsigned short h1s[128 * LD1];   // 33.8 KB

  const int tid = threadIdx.x;
  const int wave = tid >> 6;
  const int lane = tid & 63;
  const int l15 = lane & 15;
  const int q = lane >> 4;

  // ---- phase 0: gather-mean into LDS (16 threads per node, 8 node-groups) ----
  {
    const int sub = tid & 15;
    const int c = sub << 3;  // 8 shorts = 16 B per thread
#pragma unroll
    for (int it = 0; it < 8; ++it) {
      int nl = it * 16 + (tid >> 4);
      int node = blockIdx.x * 128 + nl;
      if (node < N) {
        int beg = row_ptr[node], end = row_ptr[node + 1];
        float acc[8];
#pragma unroll
        for (int j = 0; j < 8; ++j) acc[j] = 0.f;
        int e = beg;
        for (; e + 4 <= end; e += 4) {
          int s0 = csr_src[e], s1 = csr_src[e + 1], s2 = csr_src[e + 2], s3 = csr_src[e + 3];
          uint4 v0 = *(const uint4*)(xb + (size_t)s0 * K_DIM + c);
          uint4 v1 = *(const uint4*)(xb + (size_t)s1 * K_DIM + c);
          uint4 v2 = *(const uint4*)(xb + (size_t)s2 * K_DIM + c);
          uint4 v3 = *(const uint4*)(xb + (size_t)s3 * K_DIM + c);
          unsigned u[4][4] = {{v0.x, v0.y, v0.z, v0.w}, {v1.x, v1.y, v1.z, v1.w},
                              {v2.x, v2.y, v2.z, v2.w}, {v3.x, v3.y, v3.z, v3.w}};
#pragma unroll
          for (int p = 0; p < 4; ++p)
#pragma unroll
            for (int j = 0; j < 4; ++j) {
              acc[2 * j]     += __builtin_bit_cast(float, u[p][j] << 16);
              acc[2 * j + 1] += __builtin_bit_cast(float, u[p][j] & 0xffff0000u);
            }
        }
        for (; e < end; ++e) {
          int s = csr_src[e];
          uint4 v = *(const uint4*)(xb + (size_t)s * K_DIM + c);
          unsigned u[4] = {v.x, v.y, v.z, v.w};
#pragma unroll
          for (int j = 0; j < 4; ++j) {
            acc[2 * j]     += __builtin_bit_cast(float, u[j] << 16);
            acc[2 * j + 1] += __builtin_bit_cast(float, u[j] & 0xffff0000u);
          }
        }
        float inv = 1.0f / (float)max(end - beg, 1);
        uint4 o;
        unsigned* op = (unsigned*)&o;
#pragma unroll
        for (int j = 0; j < 4; ++j) {
          unsigned lo = f2b(acc[2 * j] * inv);
          unsigned hi = f2b(acc[2 * j + 1] * inv);
          op[j] = lo | (hi << 16);
        }
        *(uint4*)(aggs + nl * LDA + c) = o;
      }
    }
  }
  __syncthreads();

  // ---- phase 1 setup ----
  const int nodehalf = wave >> 1;
  const int fhalf = wave & 1;
  const int nbase_l = nodehalf * 64;
  const int nbase_g = blockIdx.x * 128 + nbase_l;
  const int fbase = fhalf * 64;

  // prefetch x fragments (global) and agg fragments (LDS)
  frag_ab ax[4][4], ag[4][4];
#pragma unroll
  for (int nt = 0; nt < 4; ++nt) {
    int m = nbase_g + nt * 16 + l15;
    int mc = (m < N) ? m : (N - 1);
    const unsigned short* xr = xb + (size_t)mc * K_DIM + q * 8;
    const unsigned short* ar = aggs + (nbase_l + nt * 16 + l15) * LDA + q * 8;
#pragma unroll
    for (int kb = 0; kb < 4; ++kb) {
      ax[nt][kb] = *(const frag_ab*)(xr + kb * 32);
      ag[nt][kb] = *(const frag_ab*)(ar + kb * 32);
    }
  }

  frag_cd acc[4][4];  // [nt][ft]
#pragma unroll
  for (int nt = 0; nt < 4; ++nt)
#pragma unroll
    for (int ft = 0; ft < 4; ++ft) acc[nt][ft] = (frag_cd)(0.f);

  const unsigned short* wsp = Ws1T + (size_t)(fbase + l15) * K_DIM + q * 8;
  const unsigned short* wnp = Wn1T + (size_t)(fbase + l15) * K_DIM + q * 8;
#pragma unroll
  for (int kb = 0; kb < 4; ++kb) {
#pragma unroll
    for (int ft = 0; ft < 4; ++ft) {
      frag_ab fs = *(const frag_ab*)(wsp + ft * (16 * K_DIM) + kb * 32);
      frag_ab fn = *(const frag_ab*)(wnp + ft * (16 * K_DIM) + kb * 32);
#pragma unroll
      for (int nt = 0; nt < 4; ++nt) {
        acc[nt][ft] = __builtin_amdgcn_mfma_f32_16x16x32_bf16(fs, ax[nt][kb], acc[nt][ft], 0, 0, 0);
        acc[nt][ft] = __builtin_amdgcn_mfma_f32_16x16x32_bf16(fn, ag[nt][kb], acc[nt][ft], 0, 0, 0);
      }
    }
  }

  // epilogue 1: relu(acc + b1) -> LDS, 8-B stores (4 consecutive feats per lane)
#pragma unroll
  for (int ft = 0; ft < 4; ++ft) {
    int f0 = fbase + ft * 16 + q * 4;
    float4 bv = *(const float4*)(b1 + f0);
#pragma unroll
    for (int nt = 0; nt < 4; ++nt) {
      int nl = nbase_l + nt * 16 + l15;
      ushort4 o;
      o.x = f2b(fmaxf(acc[nt][ft][0] + bv.x, 0.f));
      o.y = f2b(fmaxf(acc[nt][ft][1] + bv.y, 0.f));
      o.z = f2b(fmaxf(acc[nt][ft][2] + bv.z, 0.f));
      o.w = f2b(fmaxf(acc[nt][ft][3] + bv.w, 0.f));
      *(ushort4*)(h1s + nl * LD1 + f0) = o;
    }
  }
  __syncthreads();

  // ---- phase 2: h1 fragments from LDS ----
  frag_ab ah[4][4];
#pragma unroll
  for (int nt = 0; nt < 4; ++nt) {
    const unsigned short* hr = h1s + (nbase_l + nt * 16 + l15) * LD1 + q * 8;
#pragma unroll
    for (int kb = 0; kb < 4; ++kb) ah[nt][kb] = *(const frag_ab*)(hr + kb * 32);
  }

  const unsigned short* W2 = fhalf ? Wn2T : Ws2T;  // wave's output matrix
  const unsigned short* wp = W2 + (size_t)l15 * K_DIM + q * 8;
  frag_cd acc2[4][4];
#pragma unroll
  for (int nt = 0; nt < 4; ++nt)
#pragma unroll
    for (int ft = 0; ft < 4; ++ft) acc2[nt][ft] = (frag_cd)(0.f);

#pragma unroll
  for (int kb = 0; kb < 4; ++kb) {
#pragma unroll
    for (int ft = 0; ft < 4; ++ft) {
      frag_ab wf = *(const frag_ab*)(wp + ft * (16 * K_DIM) + kb * 32);
#pragma unroll
      for (int nt = 0; nt < 4; ++nt)
        acc2[nt][ft] = __builtin_amdgcn_mfma_f32_16x16x32_bf16(wf, ah[nt][kb], acc2[nt][ft], 0, 0, 0);
    }
  }

  // epilogue 2: fhalf==0 -> out fp32 (+b2), fhalf==1 -> g bf16
  if (fhalf == 0) {
#pragma unroll
    for (int ft = 0; ft < 4; ++ft) {
      int f0 = ft * 16 + q * 4;
      float4 bv = *(const float4*)(b2 + f0);
#pragma unroll
      for (int nt = 0; nt < 4; ++nt) {
        int node = nbase_g + nt * 16 + l15;
        if (node < N) {
          float4 o;
          o.x = acc2[nt][ft][0] + bv.x;
          o.y = acc2[nt][ft][1] + bv.y;
          o.z = acc2[nt][ft][2] + bv.z;
          o.w = acc2[nt][ft][3] + bv.w;
          *(float4*)(out + (size_t)node * M2 + f0) = o;
        }
      }
    }
  } else {
#pragma unroll
    for (int ft = 0; ft < 4; ++ft) {
      int f0 = ft * 16 + q * 4;
#pragma unroll
      for (int nt = 0; nt < 4; ++nt) {
        int node = nbase_g + nt * 16 + l15;
        if (node < N) {
          ushort4 o;
          o.x = f2b(acc2[nt][ft][0]);
          o.y = f2b(acc2[nt][ft][1]);
          o.z = f2b(acc2[nt][ft][2]);
          o.w = f2b(acc2[nt][ft][3]);
          *(ushort4*)(g + (size_t)node * M2 + f0) = o;
        }
      }
    }
  }
}

extern "C" void kernel_launch(void* const* d_in, const int* in_sizes, int n_in,
                              void* d_out, int out_size, void* d_ws, size_t ws_size,
                              hipStream_t stream) {
  const float* x   = (const float*)d_in[0];
  const int*   src = (const int*)d_in[1];
  const int*   dst = (const int*)d_in[2];
  const float* Ws1 = (const float*)d_in[3];
  const float* Wn1 = (const float*)d_in[4];
  const float* b1  = (const float*)d_in[5];
  const float* Ws2 = (const float*)d_in[6];
  const float* Wn2 = (const float*)d_in[7];
  const float* b2  = (const float*)d_in[8];
  float* out = (float*)d_out;

  char* ws = (char*)d_ws;
  size_t off = 0;
  auto alloc = [&](size_t bytes) {
    void* p = ws + off;
    off = (off + bytes + 4095) & ~(size_t)4095;
    return p;
  };
  int* deg       = (int*)alloc((size_t)N_NODES * 4);
  int* row_ptr   = (int*)alloc((size_t)(N_NODES + 1) * 4);
  int* cursor    = (int*)alloc((size_t)N_NODES * 4);
  int* blockSums = (int*)alloc(512 * 4);
  int* csr_src   = (int*)alloc((size_t)N_EDGES * 4);
  unsigned short* xb   = (unsigned short*)alloc((size_t)N_NODES * K_DIM * 2);
  unsigned short* g    = (unsigned short*)alloc((size_t)N_NODES * M2 * 2);
  unsigned short* Ws1T = (unsigned short*)alloc((size_t)128 * 128 * 2);
  unsigned short* Wn1T = (unsigned short*)alloc((size_t)128 * 128 * 2);
  unsigned short* Ws2T = (unsigned short*)alloc((size_t)64 * 128 * 2);
  unsigned short* Wn2T = (unsigned short*)alloc((size_t)64 * 128 * 2);

  hipMemsetAsync(deg, 0, (size_t)N_NODES * 4, stream);

  // fused conversions (x -> bf16, 4 weight transposes)
  conv_all<<<XB_BLOCKS + WB_BLOCKS, 256, 0, stream>>>(
      x, xb, Ws1, Wn1, Ws2, Wn2, Ws1T, Wn1T, Ws2T, Wn2T);

  // CSR build: deg -> 3-phase scan -> fill
  deg_count<<<(N_EDGES + 255) / 256, 256, 0, stream>>>(dst, deg, N_EDGES);
  scan1<<<SCAN_BLOCKS, 256, 0, stream>>>(deg, row_ptr, blockSums, N_NODES);
  scan2<<<1, 512, 0, stream>>>(blockSums, SCAN_BLOCKS);
  scan3<<<SCAN_BLOCKS, 256, 0, stream>>>(row_ptr, blockSums, cursor, N_NODES, N_EDGES);
  csr_fill<<<(N_EDGES + 255) / 256, 256, 0, stream>>>(src, dst, cursor, csr_src, N_EDGES);

  // fully-fused: layer-1 gather + both GEMMs (agg and h1 stay in LDS)
  sage_fused_gemm<<<(N_NODES + 127) / 128, 256, 0, stream>>>(
      xb, row_ptr, csr_src, Ws1T, Wn1T, b1, Ws2T, Wn2T, b2, out, g, N_NODES);

  // layer-2 aggregation (adds mean(g) into out)
  {
    long t = (long)N_NODES * 8;
    aggregate64_add<<<(int)((t + 255) / 256), 256, 0, stream>>>(g, row_ptr, csr_src, out, N_NODES);
  }
}

// Round 9
// 263.100 us; speedup vs baseline: 1.8501x; 1.3040x over previous
//
#include <hip/hip_runtime.h>

#define N_NODES 100000
#define N_EDGES 600000
#define K_DIM 128
#define M2 64
#define SCAN_BLOCKS ((N_NODES + 255) / 256)   // 391

using frag_ab = __attribute__((ext_vector_type(8))) short;   // 8 bf16 = 4 VGPRs
using frag_cd = __attribute__((ext_vector_type(4))) float;   // 4 fp32 acc

// fp32 -> bf16 round-to-nearest-even
__device__ __forceinline__ unsigned short f2b(float f) {
  unsigned u = __builtin_bit_cast(unsigned, f);
  u = (u + 0x7fffu + ((u >> 16) & 1u)) >> 16;
  return (unsigned short)u;
}

// ---------------- fused: x->bf16 conversion + 4 weight transposes + degree count ----------------
#define XB_BLOCKS ((N_NODES * K_DIM / 4 + 255) / 256)            // 12500
#define W_ELEMS ((128 + 128 + 64 + 64) * 128)                    // 49152
#define WB_BLOCKS ((W_ELEMS + 255) / 256)                        // 192
#define DEG_BLOCKS ((N_EDGES + 255) / 256)                       // 2344
__global__ __launch_bounds__(256) void conv_all(const float* __restrict__ x,
                                                unsigned short* __restrict__ xb,
                                                const float* __restrict__ Ws1,
                                                const float* __restrict__ Wn1,
                                                const float* __restrict__ Ws2,
                                                const float* __restrict__ Wn2,
                                                unsigned short* __restrict__ Ws1T,
                                                unsigned short* __restrict__ Wn1T,
                                                unsigned short* __restrict__ Ws2T,
                                                unsigned short* __restrict__ Wn2T,
                                                const int* __restrict__ dst,
                                                int* __restrict__ deg) {
  if (blockIdx.x < XB_BLOCKS) {
    long i = (long)blockIdx.x * 256 + threadIdx.x;
    if (i >= (long)N_NODES * K_DIM / 4) return;
    float4 v = *(const float4*)(x + i * 4);
    ushort4 o;
    o.x = f2b(v.x); o.y = f2b(v.y); o.z = f2b(v.z); o.w = f2b(v.w);
    *(ushort4*)(xb + i * 4) = o;
  } else if (blockIdx.x < XB_BLOCKS + WB_BLOCKS) {
    int i = (blockIdx.x - XB_BLOCKS) * 256 + threadIdx.x;  // global weight elem
    if (i >= W_ELEMS) return;
    const float* W;
    unsigned short* WT;
    int M, li;
    if (i < 128 * 128)               { W = Ws1; WT = Ws1T; M = 128; li = i; }
    else if (i < 2 * 128 * 128)      { W = Wn1; WT = Wn1T; M = 128; li = i - 128 * 128; }
    else if (i < 2 * 128 * 128 + 64 * 128) { W = Ws2; WT = Ws2T; M = 64; li = i - 2 * 128 * 128; }
    else                             { W = Wn2; WT = Wn2T; M = 64; li = i - 2 * 128 * 128 - 64 * 128; }
    int n = li >> 7, k = li & 127;   // li = n*128 + k
    WT[li] = f2b(W[k * M + n]);
  } else {
    int e = (blockIdx.x - XB_BLOCKS - WB_BLOCKS) * 256 + threadIdx.x;
    if (e < N_EDGES) atomicAdd(&deg[dst[e]], 1);
  }
}

// ---------------- hierarchical exclusive scan (proven: ~10 us total) ----------------
__global__ __launch_bounds__(256) void scan1(const int* __restrict__ deg,
                                             int* __restrict__ partial,
                                             int* __restrict__ blockSums, int n) {
  __shared__ int sdata[256];
  int tid = threadIdx.x;
  int i = blockIdx.x * 256 + tid;
  int v = (i < n) ? deg[i] : 0;
  sdata[tid] = v;
  __syncthreads();
#pragma unroll
  for (int off = 1; off < 256; off <<= 1) {
    int t = (tid >= off) ? sdata[tid - off] : 0;
    __syncthreads();
    sdata[tid] += t;
    __syncthreads();
  }
  if (i < n) partial[i] = sdata[tid] - v;
  if (tid == 255) blockSums[blockIdx.x] = sdata[255];
}

__global__ __launch_bounds__(512) void scan2(int* __restrict__ blockSums, int nb) {
  __shared__ int sdata[512];
  int tid = threadIdx.x;
  int v = (tid < nb) ? blockSums[tid] : 0;
  sdata[tid] = v;
  __syncthreads();
#pragma unroll
  for (int off = 1; off < 512; off <<= 1) {
    int t = (tid >= off) ? sdata[tid - off] : 0;
    __syncthreads();
    sdata[tid] += t;
    __syncthreads();
  }
  if (tid < nb) blockSums[tid] = sdata[tid] - v;
}

__global__ __launch_bounds__(256) void scan3(int* __restrict__ row_ptr,
                                             const int* __restrict__ blockSums,
                                             int* __restrict__ cursor, int n, int nE) {
  int i = blockIdx.x * 256 + threadIdx.x;
  if (i < n) {
    int val = row_ptr[i] + blockSums[i >> 8];
    row_ptr[i] = val;
    cursor[i] = val;
  }
  if (i == 0) row_ptr[n] = nE;
}

// ---------------- CSR fill ----------------
__global__ __launch_bounds__(256) void csr_fill(const int* __restrict__ src,
                                                const int* __restrict__ dst,
                                                int* __restrict__ cursor,
                                                int* __restrict__ csr_src, int nE) {
  int e = blockIdx.x * blockDim.x + threadIdx.x;
  if (e < nE) {
    int pos = atomicAdd(&cursor[dst[e]], 1);
    csr_src[pos] = src[e];
  }
}

// ---------------- gather-mean, 128 bf16 cols: 16 threads/node, 4-way pipelined ----------------
__global__ __launch_bounds__(256) void aggregate128(const unsigned short* __restrict__ xb,
                                                    const int* __restrict__ row_ptr,
                                                    const int* __restrict__ csr_src,
                                                    unsigned short* __restrict__ agg, int n) {
  int t = blockIdx.x * blockDim.x + threadIdx.x;
  int node = t >> 4;
  int c = (t & 15) << 3;  // 8 bf16 per thread
  if (node >= n) return;
  int beg = row_ptr[node], end = row_ptr[node + 1];
  float acc[8];
#pragma unroll
  for (int j = 0; j < 8; ++j) acc[j] = 0.f;

  int e = beg;
  for (; e + 4 <= end; e += 4) {
    int s0 = csr_src[e], s1 = csr_src[e + 1], s2 = csr_src[e + 2], s3 = csr_src[e + 3];
    uint4 v0 = *(const uint4*)(xb + (size_t)s0 * K_DIM + c);
    uint4 v1 = *(const uint4*)(xb + (size_t)s1 * K_DIM + c);
    uint4 v2 = *(const uint4*)(xb + (size_t)s2 * K_DIM + c);
    uint4 v3 = *(const uint4*)(xb + (size_t)s3 * K_DIM + c);
    unsigned u[4][4] = {{v0.x, v0.y, v0.z, v0.w}, {v1.x, v1.y, v1.z, v1.w},
                        {v2.x, v2.y, v2.z, v2.w}, {v3.x, v3.y, v3.z, v3.w}};
#pragma unroll
    for (int p = 0; p < 4; ++p)
#pragma unroll
      for (int j = 0; j < 4; ++j) {
        acc[2 * j]     += __builtin_bit_cast(float, u[p][j] << 16);
        acc[2 * j + 1] += __builtin_bit_cast(float, u[p][j] & 0xffff0000u);
      }
  }
  for (; e < end; ++e) {
    int s = csr_src[e];
    uint4 v = *(const uint4*)(xb + (size_t)s * K_DIM + c);
    unsigned u[4] = {v.x, v.y, v.z, v.w};
#pragma unroll
    for (int j = 0; j < 4; ++j) {
      acc[2 * j]     += __builtin_bit_cast(float, u[j] << 16);
      acc[2 * j + 1] += __builtin_bit_cast(float, u[j] & 0xffff0000u);
    }
  }
  float inv = 1.0f / (float)max(end - beg, 1);
  uint4 o;
  unsigned* op = (unsigned*)&o;
#pragma unroll
  for (int j = 0; j < 4; ++j) {
    unsigned lo = f2b(acc[2 * j] * inv);
    unsigned hi = f2b(acc[2 * j + 1] * inv);
    op[j] = lo | (hi << 16);
  }
  *(uint4*)(agg + (size_t)node * K_DIM + c) = o;
}

// ---------------- gather-mean-add, 64 bf16 cols -> out fp32: 8 threads/node, 4-way pipelined ----------------
__global__ __launch_bounds__(256) void aggregate64_add(const unsigned short* __restrict__ g,
                                                       const int* __restrict__ row_ptr,
                                                       const int* __restrict__ csr_src,
                                                       float* __restrict__ out, int n) {
  int t = blockIdx.x * blockDim.x + threadIdx.x;
  int node = t >> 3;
  int c = (t & 7) << 3;  // 8 bf16 per thread
  if (node >= n) return;
  int beg = row_ptr[node], end = row_ptr[node + 1];
  float acc[8];
#pragma unroll
  for (int j = 0; j < 8; ++j) acc[j] = 0.f;

  int e = beg;
  for (; e + 4 <= end; e += 4) {
    int s0 = csr_src[e], s1 = csr_src[e + 1], s2 = csr_src[e + 2], s3 = csr_src[e + 3];
    uint4 v0 = *(const uint4*)(g + (size_t)s0 * M2 + c);
    uint4 v1 = *(const uint4*)(g + (size_t)s1 * M2 + c);
    uint4 v2 = *(const uint4*)(g + (size_t)s2 * M2 + c);
    uint4 v3 = *(const uint4*)(g + (size_t)s3 * M2 + c);
    unsigned u[4][4] = {{v0.x, v0.y, v0.z, v0.w}, {v1.x, v1.y, v1.z, v1.w},
                        {v2.x, v2.y, v2.z, v2.w}, {v3.x, v3.y, v3.z, v3.w}};
#pragma unroll
    for (int p = 0; p < 4; ++p)
#pragma unroll
      for (int j = 0; j < 4; ++j) {
        acc[2 * j]     += __builtin_bit_cast(float, u[p][j] << 16);
        acc[2 * j + 1] += __builtin_bit_cast(float, u[p][j] & 0xffff0000u);
      }
  }
  for (; e < end; ++e) {
    int s = csr_src[e];
    uint4 v = *(const uint4*)(g + (size_t)s * M2 + c);
    unsigned u[4] = {v.x, v.y, v.z, v.w};
#pragma unroll
    for (int j = 0; j < 4; ++j) {
      acc[2 * j]     += __builtin_bit_cast(float, u[j] << 16);
      acc[2 * j + 1] += __builtin_bit_cast(float, u[j] & 0xffff0000u);
    }
  }
  float inv = 1.0f / (float)max(end - beg, 1);
  float* op = out + (size_t)node * M2 + c;
  float4 o0 = *(float4*)(op);
  float4 o1 = *(float4*)(op + 4);
  o0.x += acc[0] * inv; o0.y += acc[1] * inv; o0.z += acc[2] * inv; o0.w += acc[3] * inv;
  o1.x += acc[4] * inv; o1.y += acc[5] * inv; o1.z += acc[6] * inv; o1.w += acc[7] * inv;
  *(float4*)(op) = o0;
  *(float4*)(op + 4) = o1;
}

// ---------------- fused both-layer GEMM, 128-node blocks (R5 structure: 53 us) ----------------
// Phase 1: h1 = relu(xb@Ws1 + aggb@Wn1 + b1) -> LDS (128 nodes x 128 feat)
// Phase 2: out = h1@Ws2 + b2 (fp32), g = h1@Wn2 (bf16)
// Operand-swapped MFMA: A = weight rows (feat=lane&15), B = node rows (node=lane&15);
// D: node = lane&15, feat = q*4+r -> vectorized stores.
#define LD1 132   // LDS row stride (264 B)
__global__ __launch_bounds__(256) void sage_fused_gemm(const unsigned short* __restrict__ xb,
                                                       const unsigned short* __restrict__ aggb,
                                                       const unsigned short* __restrict__ Ws1T,
                                                       const unsigned short* __restrict__ Wn1T,
                                                       const float* __restrict__ b1,
                                                       const unsigned short* __restrict__ Ws2T,
                                                       const unsigned short* __restrict__ Wn2T,
                                                       const float* __restrict__ b2,
                                                       float* __restrict__ out,
                                                       unsigned short* __restrict__ g, int N) {
  __shared__ unsigned short h1s[128 * LD1];

  const int tid = threadIdx.x;
  const int wave = tid >> 6;
  const int lane = tid & 63;
  const int l15 = lane & 15;
  const int q = lane >> 4;
  const int nodehalf = wave >> 1;
  const int fhalf = wave & 1;
  const int nbase_l = nodehalf * 64;
  const int nbase_g = blockIdx.x * 128 + nbase_l;
  const int fbase = fhalf * 64;

  // ---- phase 1: prefetch all x/agg fragments (32 outstanding 16-B loads) ----
  frag_ab ax[4][4], ag[4][4];
#pragma unroll
  for (int nt = 0; nt < 4; ++nt) {
    int m = nbase_g + nt * 16 + l15;
    int mc = (m < N) ? m : (N - 1);
    const unsigned short* xr = xb + (size_t)mc * K_DIM + q * 8;
    const unsigned short* gr = aggb + (size_t)mc * K_DIM + q * 8;
#pragma unroll
    for (int kb = 0; kb < 4; ++kb) {
      ax[nt][kb] = *(const frag_ab*)(xr + kb * 32);
      ag[nt][kb] = *(const frag_ab*)(gr + kb * 32);
    }
  }

  frag_cd acc[4][4];  // [nt][ft]
#pragma unroll
  for (int nt = 0; nt < 4; ++nt)
#pragma unroll
    for (int ft = 0; ft < 4; ++ft) acc[nt][ft] = (frag_cd)(0.f);

  const unsigned short* wsp = Ws1T + (size_t)(fbase + l15) * K_DIM + q * 8;
  const unsigned short* wnp = Wn1T + (size_t)(fbase + l15) * K_DIM + q * 8;
#pragma unroll
  for (int kb = 0; kb < 4; ++kb) {
#pragma unroll
    for (int ft = 0; ft < 4; ++ft) {
      frag_ab fs = *(const frag_ab*)(wsp + ft * (16 * K_DIM) + kb * 32);
      frag_ab fn = *(const frag_ab*)(wnp + ft * (16 * K_DIM) + kb * 32);
#pragma unroll
      for (int nt = 0; nt < 4; ++nt) {
        acc[nt][ft] = __builtin_amdgcn_mfma_f32_16x16x32_bf16(fs, ax[nt][kb], acc[nt][ft], 0, 0, 0);
        acc[nt][ft] = __builtin_amdgcn_mfma_f32_16x16x32_bf16(fn, ag[nt][kb], acc[nt][ft], 0, 0, 0);
      }
    }
  }

  // epilogue 1: relu(acc + b1) -> LDS, 8-B stores (4 consecutive feats per lane)
#pragma unroll
  for (int ft = 0; ft < 4; ++ft) {
    int f0 = fbase + ft * 16 + q * 4;
    float4 bv = *(const float4*)(b1 + f0);
#pragma unroll
    for (int nt = 0; nt < 4; ++nt) {
      int nl = nbase_l + nt * 16 + l15;
      ushort4 o;
      o.x = f2b(fmaxf(acc[nt][ft][0] + bv.x, 0.f));
      o.y = f2b(fmaxf(acc[nt][ft][1] + bv.y, 0.f));
      o.z = f2b(fmaxf(acc[nt][ft][2] + bv.z, 0.f));
      o.w = f2b(fmaxf(acc[nt][ft][3] + bv.w, 0.f));
      *(ushort4*)(h1s + nl * LD1 + f0) = o;
    }
  }
  __syncthreads();

  // ---- phase 2: h1 fragments from LDS ----
  frag_ab ah[4][4];
#pragma unroll
  for (int nt = 0; nt < 4; ++nt) {
    const unsigned short* hr = h1s + (nbase_l + nt * 16 + l15) * LD1 + q * 8;
#pragma unroll
    for (int kb = 0; kb < 4; ++kb) ah[nt][kb] = *(const frag_ab*)(hr + kb * 32);
  }

  const unsigned short* W2 = fhalf ? Wn2T : Ws2T;  // wave's output matrix
  const unsigned short* wp = W2 + (size_t)l15 * K_DIM + q * 8;
  frag_cd acc2[4][4];
#pragma unroll
  for (int nt = 0; nt < 4; ++nt)
#pragma unroll
    for (int ft = 0; ft < 4; ++ft) acc2[nt][ft] = (frag_cd)(0.f);

#pragma unroll
  for (int kb = 0; kb < 4; ++kb) {
#pragma unroll
    for (int ft = 0; ft < 4; ++ft) {
      frag_ab wf = *(const frag_ab*)(wp + ft * (16 * K_DIM) + kb * 32);
#pragma unroll
      for (int nt = 0; nt < 4; ++nt)
        acc2[nt][ft] = __builtin_amdgcn_mfma_f32_16x16x32_bf16(wf, ah[nt][kb], acc2[nt][ft], 0, 0, 0);
    }
  }

  // epilogue 2: fhalf==0 -> out fp32 (+b2), fhalf==1 -> g bf16
  if (fhalf == 0) {
#pragma unroll
    for (int ft = 0; ft < 4; ++ft) {
      int f0 = ft * 16 + q * 4;
      float4 bv = *(const float4*)(b2 + f0);
#pragma unroll
      for (int nt = 0; nt < 4; ++nt) {
        int node = nbase_g + nt * 16 + l15;
        if (node < N) {
          float4 o;
          o.x = acc2[nt][ft][0] + bv.x;
          o.y = acc2[nt][ft][1] + bv.y;
          o.z = acc2[nt][ft][2] + bv.z;
          o.w = acc2[nt][ft][3] + bv.w;
          *(float4*)(out + (size_t)node * M2 + f0) = o;
        }
      }
    }
  } else {
#pragma unroll
    for (int ft = 0; ft < 4; ++ft) {
      int f0 = ft * 16 + q * 4;
#pragma unroll
      for (int nt = 0; nt < 4; ++nt) {
        int node = nbase_g + nt * 16 + l15;
        if (node < N) {
          ushort4 o;
          o.x = f2b(acc2[nt][ft][0]);
          o.y = f2b(acc2[nt][ft][1]);
          o.z = f2b(acc2[nt][ft][2]);
          o.w = f2b(acc2[nt][ft][3]);
          *(ushort4*)(g + (size_t)node * M2 + f0) = o;
        }
      }
    }
  }
}

extern "C" void kernel_launch(void* const* d_in, const int* in_sizes, int n_in,
                              void* d_out, int out_size, void* d_ws, size_t ws_size,
                              hipStream_t stream) {
  const float* x   = (const float*)d_in[0];
  const int*   src = (const int*)d_in[1];
  const int*   dst = (const int*)d_in[2];
  const float* Ws1 = (const float*)d_in[3];
  const float* Wn1 = (const float*)d_in[4];
  const float* b1  = (const float*)d_in[5];
  const float* Ws2 = (const float*)d_in[6];
  const float* Wn2 = (const float*)d_in[7];
  const float* b2  = (const float*)d_in[8];
  float* out = (float*)d_out;

  char* ws = (char*)d_ws;
  size_t off = 0;
  auto alloc = [&](size_t bytes) {
    void* p = ws + off;
    off = (off + bytes + 4095) & ~(size_t)4095;
    return p;
  };
  int* deg       = (int*)alloc((size_t)N_NODES * 4);
  int* row_ptr   = (int*)alloc((size_t)(N_NODES + 1) * 4);
  int* cursor    = (int*)alloc((size_t)N_NODES * 4);
  int* blockSums = (int*)alloc(512 * 4);
  int* csr_src   = (int*)alloc((size_t)N_EDGES * 4);
  unsigned short* xb   = (unsigned short*)alloc((size_t)N_NODES * K_DIM * 2);
  unsigned short* aggb = (unsigned short*)alloc((size_t)N_NODES * K_DIM * 2);
  unsigned short* g    = (unsigned short*)alloc((size_t)N_NODES * M2 * 2);
  unsigned short* Ws1T = (unsigned short*)alloc((size_t)128 * 128 * 2);
  unsigned short* Wn1T = (unsigned short*)alloc((size_t)128 * 128 * 2);
  unsigned short* Ws2T = (unsigned short*)alloc((size_t)64 * 128 * 2);
  unsigned short* Wn2T = (unsigned short*)alloc((size_t)64 * 128 * 2);

  hipMemsetAsync(deg, 0, (size_t)N_NODES * 4, stream);

  // fused conversions (x -> bf16, weight transposes) + degree count
  conv_all<<<XB_BLOCKS + WB_BLOCKS + DEG_BLOCKS, 256, 0, stream>>>(
      x, xb, Ws1, Wn1, Ws2, Wn2, Ws1T, Wn1T, Ws2T, Wn2T, dst, deg);

  // CSR build: 3-phase scan -> fill
  scan1<<<SCAN_BLOCKS, 256, 0, stream>>>(deg, row_ptr, blockSums, N_NODES);
  scan2<<<1, 512, 0, stream>>>(blockSums, SCAN_BLOCKS);
  scan3<<<SCAN_BLOCKS, 256, 0, stream>>>(row_ptr, blockSums, cursor, N_NODES, N_EDGES);
  csr_fill<<<(N_EDGES + 255) / 256, 256, 0, stream>>>(src, dst, cursor, csr_src, N_EDGES);

  // layer-1 aggregation (gather-mean, 4-way pipelined)
  {
    long t = (long)N_NODES * 16;
    aggregate128<<<(int)((t + 255) / 256), 256, 0, stream>>>(xb, row_ptr, csr_src, aggb, N_NODES);
  }

  // fused layer-1 + layer-2 GEMMs (h1 stays in LDS)
  sage_fused_gemm<<<(N_NODES + 127) / 128, 256, 0, stream>>>(
      xb, aggb, Ws1T, Wn1T, b1, Ws2T, Wn2T, b2, out, g, N_NODES);

  // layer-2 aggregation (adds mean(g) into out)
  {
    long t = (long)N_NODES * 8;
    aggregate64_add<<<(int)((t + 255) / 256), 256, 0, stream>>>(g, row_ptr, csr_src, out, N_NODES);
  }
}

// Round 10
// 262.725 us; speedup vs baseline: 1.8528x; 1.0014x over previous
//
#include <hip/hip_runtime.h>

#define N_NODES 100000
#define N_EDGES 600000
#define K_DIM 128
#define M2 64
#define SCAN_BLOCKS ((N_NODES + 255) / 256)   // 391

using frag_ab = __attribute__((ext_vector_type(8))) short;   // 8 bf16 = 4 VGPRs
using frag_cd = __attribute__((ext_vector_type(4))) float;   // 4 fp32 acc

// fp32 -> bf16 round-to-nearest-even
__device__ __forceinline__ unsigned short f2b(float f) {
  unsigned u = __builtin_bit_cast(unsigned, f);
  u = (u + 0x7fffu + ((u >> 16) & 1u)) >> 16;
  return (unsigned short)u;
}

// ---------------- fused: x->bf16 conversion + 4 weight transposes + degree count ----------------
#define XB_BLOCKS ((N_NODES * K_DIM / 4 + 255) / 256)            // 12500
#define W_ELEMS ((128 + 128 + 64 + 64) * 128)                    // 49152
#define WB_BLOCKS ((W_ELEMS + 255) / 256)                        // 192
#define DEG_BLOCKS ((N_EDGES + 255) / 256)                       // 2344
__global__ __launch_bounds__(256) void conv_all(const float* __restrict__ x,
                                                unsigned short* __restrict__ xb,
                                                const float* __restrict__ Ws1,
                                                const float* __restrict__ Wn1,
                                                const float* __restrict__ Ws2,
                                                const float* __restrict__ Wn2,
                                                unsigned short* __restrict__ Ws1T,
                                                unsigned short* __restrict__ Wn1T,
                                                unsigned short* __restrict__ Ws2T,
                                                unsigned short* __restrict__ Wn2T,
                                                const int* __restrict__ dst,
                                                int* __restrict__ deg) {
  if (blockIdx.x < XB_BLOCKS) {
    long i = (long)blockIdx.x * 256 + threadIdx.x;
    if (i >= (long)N_NODES * K_DIM / 4) return;
    float4 v = *(const float4*)(x + i * 4);
    ushort4 o;
    o.x = f2b(v.x); o.y = f2b(v.y); o.z = f2b(v.z); o.w = f2b(v.w);
    *(ushort4*)(xb + i * 4) = o;
  } else if (blockIdx.x < XB_BLOCKS + WB_BLOCKS) {
    int i = (blockIdx.x - XB_BLOCKS) * 256 + threadIdx.x;  // global weight elem
    if (i >= W_ELEMS) return;
    const float* W;
    unsigned short* WT;
    int M, li;
    if (i < 128 * 128)               { W = Ws1; WT = Ws1T; M = 128; li = i; }
    else if (i < 2 * 128 * 128)      { W = Wn1; WT = Wn1T; M = 128; li = i - 128 * 128; }
    else if (i < 2 * 128 * 128 + 64 * 128) { W = Ws2; WT = Ws2T; M = 64; li = i - 2 * 128 * 128; }
    else                             { W = Wn2; WT = Wn2T; M = 64; li = i - 2 * 128 * 128 - 64 * 128; }
    int n = li >> 7, k = li & 127;   // li = n*128 + k
    WT[li] = f2b(W[k * M + n]);
  } else {
    int e = (blockIdx.x - XB_BLOCKS - WB_BLOCKS) * 256 + threadIdx.x;
    if (e < N_EDGES) atomicAdd(&deg[dst[e]], 1);
  }
}

// ---------------- scan stage 1: per-256-block exclusive partials + block sums ----------------
__global__ __launch_bounds__(256) void scan1(const int* __restrict__ deg,
                                             int* __restrict__ partial,
                                             int* __restrict__ blockSums, int n) {
  __shared__ int sdata[256];
  int tid = threadIdx.x;
  int i = blockIdx.x * 256 + tid;
  int v = (i < n) ? deg[i] : 0;
  sdata[tid] = v;
  __syncthreads();
#pragma unroll
  for (int off = 1; off < 256; off <<= 1) {
    int t = (tid >= off) ? sdata[tid - off] : 0;
    __syncthreads();
    sdata[tid] += t;
    __syncthreads();
  }
  if (i < n) partial[i] = sdata[tid] - v;
  if (tid == 255) blockSums[blockIdx.x] = sdata[255];
}

// ---------------- scan stage 2 (fused old scan2+scan3): every block redundantly scans
// blockSums (391 ints) in LDS, then finalizes its 512-node slice of row_ptr/cursor. ----------------
__global__ __launch_bounds__(512) void scanB(int* __restrict__ row_ptr,   // partial in, full out
                                             const int* __restrict__ blockSums,
                                             int* __restrict__ cursor, int n, int nE) {
  __shared__ int bs[512];
  int tid = threadIdx.x;
  int v = (tid < SCAN_BLOCKS) ? blockSums[tid] : 0;
  bs[tid] = v;
  __syncthreads();
#pragma unroll
  for (int off = 1; off < 512; off <<= 1) {
    int t = (tid >= off) ? bs[tid - off] : 0;
    __syncthreads();
    bs[tid] += t;
    __syncthreads();
  }
  // bs now inclusive; exclusive = bs[j] - orig[j]; store exclusive back
  bs[tid] -= v;
  __syncthreads();

  int i = blockIdx.x * 512 + tid;
  if (i < n) {
    int val = row_ptr[i] + bs[i >> 8];
    row_ptr[i] = val;
    cursor[i] = val;
  }
  if (i == 0) row_ptr[n] = nE;
}

// ---------------- CSR fill ----------------
__global__ __launch_bounds__(256) void csr_fill(const int* __restrict__ src,
                                                const int* __restrict__ dst,
                                                int* __restrict__ cursor,
                                                int* __restrict__ csr_src, int nE) {
  int e = blockIdx.x * blockDim.x + threadIdx.x;
  if (e < nE) {
    int pos = atomicAdd(&cursor[dst[e]], 1);
    csr_src[pos] = src[e];
  }
}

// ---------------- gather-mean, 128 bf16 cols: 16 threads/node, 8-wide predicated batches ----------------
__global__ __launch_bounds__(256) void aggregate128(const unsigned short* __restrict__ xb,
                                                    const int* __restrict__ row_ptr,
                                                    const int* __restrict__ csr_src,
                                                    unsigned short* __restrict__ agg, int n) {
  int t = blockIdx.x * blockDim.x + threadIdx.x;
  int node = t >> 4;
  int c = (t & 15) << 3;  // 8 bf16 per thread
  if (node >= n) return;
  int beg = row_ptr[node], end = row_ptr[node + 1];
  float acc[8];
#pragma unroll
  for (int j = 0; j < 8; ++j) acc[j] = 0.f;

  if (end > beg) {
    for (int e0 = beg; e0 < end; e0 += 8) {
      int idx[8];
#pragma unroll
      for (int p = 0; p < 8; ++p) idx[p] = csr_src[min(e0 + p, end - 1)];
      uint4 v[8];
#pragma unroll
      for (int p = 0; p < 8; ++p) v[p] = *(const uint4*)(xb + (size_t)idx[p] * K_DIM + c);
#pragma unroll
      for (int p = 0; p < 8; ++p) {
        float m = (e0 + p < end) ? 1.f : 0.f;
        unsigned u[4] = {v[p].x, v[p].y, v[p].z, v[p].w};
#pragma unroll
        for (int j = 0; j < 4; ++j) {
          acc[2 * j]     += m * __builtin_bit_cast(float, u[j] << 16);
          acc[2 * j + 1] += m * __builtin_bit_cast(float, u[j] & 0xffff0000u);
        }
      }
    }
  }
  float inv = 1.0f / (float)max(end - beg, 1);
  uint4 o;
  unsigned* op = (unsigned*)&o;
#pragma unroll
  for (int j = 0; j < 4; ++j) {
    unsigned lo = f2b(acc[2 * j] * inv);
    unsigned hi = f2b(acc[2 * j + 1] * inv);
    op[j] = lo | (hi << 16);
  }
  *(uint4*)(agg + (size_t)node * K_DIM + c) = o;
}

// ---------------- gather-mean-add, 64 bf16 cols -> out fp32: 8 threads/node, 8-wide batches ----------------
__global__ __launch_bounds__(256) void aggregate64_add(const unsigned short* __restrict__ g,
                                                       const int* __restrict__ row_ptr,
                                                       const int* __restrict__ csr_src,
                                                       float* __restrict__ out, int n) {
  int t = blockIdx.x * blockDim.x + threadIdx.x;
  int node = t >> 3;
  int c = (t & 7) << 3;  // 8 bf16 per thread
  if (node >= n) return;
  int beg = row_ptr[node], end = row_ptr[node + 1];
  float acc[8];
#pragma unroll
  for (int j = 0; j < 8; ++j) acc[j] = 0.f;

  if (end > beg) {
    for (int e0 = beg; e0 < end; e0 += 8) {
      int idx[8];
#pragma unroll
      for (int p = 0; p < 8; ++p) idx[p] = csr_src[min(e0 + p, end - 1)];
      uint4 v[8];
#pragma unroll
      for (int p = 0; p < 8; ++p) v[p] = *(const uint4*)(g + (size_t)idx[p] * M2 + c);
#pragma unroll
      for (int p = 0; p < 8; ++p) {
        float m = (e0 + p < end) ? 1.f : 0.f;
        unsigned u[4] = {v[p].x, v[p].y, v[p].z, v[p].w};
#pragma unroll
        for (int j = 0; j < 4; ++j) {
          acc[2 * j]     += m * __builtin_bit_cast(float, u[j] << 16);
          acc[2 * j + 1] += m * __builtin_bit_cast(float, u[j] & 0xffff0000u);
        }
      }
    }
  }
  float inv = 1.0f / (float)max(end - beg, 1);
  float* op = out + (size_t)node * M2 + c;
  float4 o0 = *(float4*)(op);
  float4 o1 = *(float4*)(op + 4);
  o0.x += acc[0] * inv; o0.y += acc[1] * inv; o0.z += acc[2] * inv; o0.w += acc[3] * inv;
  o1.x += acc[4] * inv; o1.y += acc[5] * inv; o1.z += acc[6] * inv; o1.w += acc[7] * inv;
  *(float4*)(op) = o0;
  *(float4*)(op + 4) = o1;
}

// ---------------- fused both-layer GEMM, 128-node blocks (measured 52 us) ----------------
// Phase 1: h1 = relu(xb@Ws1 + aggb@Wn1 + b1) -> LDS (128 nodes x 128 feat)
// Phase 2: out = h1@Ws2 + b2 (fp32), g = h1@Wn2 (bf16)
// Operand-swapped MFMA: A = weight rows (feat=lane&15), B = node rows (node=lane&15);
// D: node = lane&15, feat = q*4+r -> vectorized stores.
#define LD1 132   // LDS row stride (264 B)
__global__ __launch_bounds__(256) void sage_fused_gemm(const unsigned short* __restrict__ xb,
                                                       const unsigned short* __restrict__ aggb,
                                                       const unsigned short* __restrict__ Ws1T,
                                                       const unsigned short* __restrict__ Wn1T,
                                                       const float* __restrict__ b1,
                                                       const unsigned short* __restrict__ Ws2T,
                                                       const unsigned short* __restrict__ Wn2T,
                                                       const float* __restrict__ b2,
                                                       float* __restrict__ out,
                                                       unsigned short* __restrict__ g, int N) {
  __shared__ unsigned short h1s[128 * LD1];

  const int tid = threadIdx.x;
  const int wave = tid >> 6;
  const int lane = tid & 63;
  const int l15 = lane & 15;
  const int q = lane >> 4;
  const int nodehalf = wave >> 1;
  const int fhalf = wave & 1;
  const int nbase_l = nodehalf * 64;
  const int nbase_g = blockIdx.x * 128 + nbase_l;
  const int fbase = fhalf * 64;

  // ---- phase 1: prefetch all x/agg fragments (32 outstanding 16-B loads) ----
  frag_ab ax[4][4], ag[4][4];
#pragma unroll
  for (int nt = 0; nt < 4; ++nt) {
    int m = nbase_g + nt * 16 + l15;
    int mc = (m < N) ? m : (N - 1);
    const unsigned short* xr = xb + (size_t)mc * K_DIM + q * 8;
    const unsigned short* gr = aggb + (size_t)mc * K_DIM + q * 8;
#pragma unroll
    for (int kb = 0; kb < 4; ++kb) {
      ax[nt][kb] = *(const frag_ab*)(xr + kb * 32);
      ag[nt][kb] = *(const frag_ab*)(gr + kb * 32);
    }
  }

  frag_cd acc[4][4];  // [nt][ft]
#pragma unroll
  for (int nt = 0; nt < 4; ++nt)
#pragma unroll
    for (int ft = 0; ft < 4; ++ft) acc[nt][ft] = (frag_cd)(0.f);

  const unsigned short* wsp = Ws1T + (size_t)(fbase + l15) * K_DIM + q * 8;
  const unsigned short* wnp = Wn1T + (size_t)(fbase + l15) * K_DIM + q * 8;
#pragma unroll
  for (int kb = 0; kb < 4; ++kb) {
#pragma unroll
    for (int ft = 0; ft < 4; ++ft) {
      frag_ab fs = *(const frag_ab*)(wsp + ft * (16 * K_DIM) + kb * 32);
      frag_ab fn = *(const frag_ab*)(wnp + ft * (16 * K_DIM) + kb * 32);
#pragma unroll
      for (int nt = 0; nt < 4; ++nt) {
        acc[nt][ft] = __builtin_amdgcn_mfma_f32_16x16x32_bf16(fs, ax[nt][kb], acc[nt][ft], 0, 0, 0);
        acc[nt][ft] = __builtin_amdgcn_mfma_f32_16x16x32_bf16(fn, ag[nt][kb], acc[nt][ft], 0, 0, 0);
      }
    }
  }

  // epilogue 1: relu(acc + b1) -> LDS, 8-B stores (4 consecutive feats per lane)
#pragma unroll
  for (int ft = 0; ft < 4; ++ft) {
    int f0 = fbase + ft * 16 + q * 4;
    float4 bv = *(const float4*)(b1 + f0);
#pragma unroll
    for (int nt = 0; nt < 4; ++nt) {
      int nl = nbase_l + nt * 16 + l15;
      ushort4 o;
      o.x = f2b(fmaxf(acc[nt][ft][0] + bv.x, 0.f));
      o.y = f2b(fmaxf(acc[nt][ft][1] + bv.y, 0.f));
      o.z = f2b(fmaxf(acc[nt][ft][2] + bv.z, 0.f));
      o.w = f2b(fmaxf(acc[nt][ft][3] + bv.w, 0.f));
      *(ushort4*)(h1s + nl * LD1 + f0) = o;
    }
  }
  __syncthreads();

  // ---- phase 2: h1 fragments from LDS ----
  frag_ab ah[4][4];
#pragma unroll
  for (int nt = 0; nt < 4; ++nt) {
    const unsigned short* hr = h1s + (nbase_l + nt * 16 + l15) * LD1 + q * 8;
#pragma unroll
    for (int kb = 0; kb < 4; ++kb) ah[nt][kb] = *(const frag_ab*)(hr + kb * 32);
  }

  const unsigned short* W2 = fhalf ? Wn2T : Ws2T;  // wave's output matrix
  const unsigned short* wp = W2 + (size_t)l15 * K_DIM + q * 8;
  frag_cd acc2[4][4];
#pragma unroll
  for (int nt = 0; nt < 4; ++nt)
#pragma unroll
    for (int ft = 0; ft < 4; ++ft) acc2[nt][ft] = (frag_cd)(0.f);

#pragma unroll
  for (int kb = 0; kb < 4; ++kb) {
#pragma unroll
    for (int ft = 0; ft < 4; ++ft) {
      frag_ab wf = *(const frag_ab*)(wp + ft * (16 * K_DIM) + kb * 32);
#pragma unroll
      for (int nt = 0; nt < 4; ++nt)
        acc2[nt][ft] = __builtin_amdgcn_mfma_f32_16x16x32_bf16(wf, ah[nt][kb], acc2[nt][ft], 0, 0, 0);
    }
  }

  // epilogue 2: fhalf==0 -> out fp32 (+b2), fhalf==1 -> g bf16
  if (fhalf == 0) {
#pragma unroll
    for (int ft = 0; ft < 4; ++ft) {
      int f0 = ft * 16 + q * 4;
      float4 bv = *(const float4*)(b2 + f0);
#pragma unroll
      for (int nt = 0; nt < 4; ++nt) {
        int node = nbase_g + nt * 16 + l15;
        if (node < N) {
          float4 o;
          o.x = acc2[nt][ft][0] + bv.x;
          o.y = acc2[nt][ft][1] + bv.y;
          o.z = acc2[nt][ft][2] + bv.z;
          o.w = acc2[nt][ft][3] + bv.w;
          *(float4*)(out + (size_t)node * M2 + f0) = o;
        }
      }
    }
  } else {
#pragma unroll
    for (int ft = 0; ft < 4; ++ft) {
      int f0 = ft * 16 + q * 4;
#pragma unroll
      for (int nt = 0; nt < 4; ++nt) {
        int node = nbase_g + nt * 16 + l15;
        if (node < N) {
          ushort4 o;
          o.x = f2b(acc2[nt][ft][0]);
          o.y = f2b(acc2[nt][ft][1]);
          o.z = f2b(acc2[nt][ft][2]);
          o.w = f2b(acc2[nt][ft][3]);
          *(ushort4*)(g + (size_t)node * M2 + f0) = o;
        }
      }
    }
  }
}

extern "C" void kernel_launch(void* const* d_in, const int* in_sizes, int n_in,
                              void* d_out, int out_size, void* d_ws, size_t ws_size,
                              hipStream_t stream) {
  const float* x   = (const float*)d_in[0];
  const int*   src = (const int*)d_in[1];
  const int*   dst = (const int*)d_in[2];
  const float* Ws1 = (const float*)d_in[3];
  const float* Wn1 = (const float*)d_in[4];
  const float* b1  = (const float*)d_in[5];
  const float* Ws2 = (const float*)d_in[6];
  const float* Wn2 = (const float*)d_in[7];
  const float* b2  = (const float*)d_in[8];
  float* out = (float*)d_out;

  char* ws = (char*)d_ws;
  size_t off = 0;
  auto alloc = [&](size_t bytes) {
    void* p = ws + off;
    off = (off + bytes + 4095) & ~(size_t)4095;
    return p;
  };
  int* deg       = (int*)alloc((size_t)N_NODES * 4);
  int* row_ptr   = (int*)alloc((size_t)(N_NODES + 1) * 4);
  int* cursor    = (int*)alloc((size_t)N_NODES * 4);
  int* blockSums = (int*)alloc(512 * 4);
  int* csr_src   = (int*)alloc((size_t)N_EDGES * 4);
  unsigned short* xb   = (unsigned short*)alloc((size_t)N_NODES * K_DIM * 2);
  unsigned short* aggb = (unsigned short*)alloc((size_t)N_NODES * K_DIM * 2);
  unsigned short* g    = (unsigned short*)alloc((size_t)N_NODES * M2 * 2);
  unsigned short* Ws1T = (unsigned short*)alloc((size_t)128 * 128 * 2);
  unsigned short* Wn1T = (unsigned short*)alloc((size_t)128 * 128 * 2);
  unsigned short* Ws2T = (unsigned short*)alloc((size_t)64 * 128 * 2);
  unsigned short* Wn2T = (unsigned short*)alloc((size_t)64 * 128 * 2);

  hipMemsetAsync(deg, 0, (size_t)N_NODES * 4, stream);

  // fused conversions (x -> bf16, weight transposes) + degree count
  conv_all<<<XB_BLOCKS + WB_BLOCKS + DEG_BLOCKS, 256, 0, stream>>>(
      x, xb, Ws1, Wn1, Ws2, Wn2, Ws1T, Wn1T, Ws2T, Wn2T, dst, deg);

  // CSR build: 2-stage scan -> fill
  scan1<<<SCAN_BLOCKS, 256, 0, stream>>>(deg, row_ptr, blockSums, N_NODES);
  scanB<<<(N_NODES + 511) / 512, 512, 0, stream>>>(row_ptr, blockSums, cursor, N_NODES, N_EDGES);
  csr_fill<<<(N_EDGES + 255) / 256, 256, 0, stream>>>(src, dst, cursor, csr_src, N_EDGES);

  // layer-1 aggregation (gather-mean, 8-wide predicated batches)
  {
    long t = (long)N_NODES * 16;
    aggregate128<<<(int)((t + 255) / 256), 256, 0, stream>>>(xb, row_ptr, csr_src, aggb, N_NODES);
  }

  // fused layer-1 + layer-2 GEMMs (h1 stays in LDS)
  sage_fused_gemm<<<(N_NODES + 127) / 128, 256, 0, stream>>>(
      xb, aggb, Ws1T, Wn1T, b1, Ws2T, Wn2T, b2, out, g, N_NODES);

  // layer-2 aggregation (adds mean(g) into out)
  {
    long t = (long)N_NODES * 8;
    aggregate64_add<<<(int)((t + 255) / 256), 256, 0, stream>>>(g, row_ptr, csr_src, out, N_NODES);
  }
}